// Round 3
// baseline (993.216 us; speedup 1.0000x reference)
//
#include <hip/hip_runtime.h>
#include <float.h>

// Fused sparsemax attention, fp32 in/out. B=64, Lq=Lk=1024, D=64.
// d_out = out[B,Lq,D] ++ attn[B,Lq,Lk], fp32.
//
// Single fused kernel (block = 64 q-rows = 4 waves, wave owns 16 rows):
//  - per 128-key tile: K staged hi/lo bf16 in LDS, scores via 3x MFMA
//    (hi*hi + lo*hi + hi*lo ~ fp32 accuracy, proven in R2), mask applied,
//    per-row running max in registers, CANDIDATES (s > rowmax-1) appended
//    to per-row LDS lists (tau >= rowmax-1 proves everything else is 0),
//    attn tile zero-filled coalesced.
//  - epilogue: per-row Michelot tau on <=96 candidates, scatter support
//    into attn, batched v-gather PV for out.
//  - overflow (>96 candidates, ~never: E[n]~33): exact fp32 full-row
//    recompute fallback.
// Raw scores are never written: saves the 268+268 MB round-trip of R2.

#define BATCH  64
#define SEQQ   1024
#define SEQK   1024
#define DHEAD  64
#define CAP    96
#define CSTR   97   // padded list stride (97 floats) to spread LDS banks

typedef short short8 __attribute__((ext_vector_type(8)));
typedef float f32x4  __attribute__((ext_vector_type(4)));

__device__ __forceinline__ unsigned short bf16_rne(float f) {
    unsigned u = __float_as_uint(f);
    u += 0x7fffu + ((u >> 16) & 1u);
    return (unsigned short)(u >> 16);
}

__device__ __forceinline__ void cvt_hilo8(const float* fv, float scale,
                                          short8* hi, short8* lo) {
    #pragma unroll
    for (int j = 0; j < 8; ++j) {
        float f = fv[j] * scale;
        unsigned short hb = bf16_rne(f);
        float hf = __uint_as_float((unsigned)hb << 16);
        (*hi)[j] = (short)hb;
        (*lo)[j] = (short)bf16_rne(f - hf);
    }
}

// ---- mask dtype detector: 1-byte bools vs int32 0/1 (proven R1/R2) --------
__global__ void detect_mask_fmt(const unsigned char* __restrict__ m,
                                int* __restrict__ flag) {
    __shared__ int s_found;
    if (threadIdx.x == 0) s_found = 0;
    __syncthreads();
    int found = 0;
    for (int o = threadIdx.x; o < 65536; o += 256) {
        if ((o & 3) != 0 && m[o] != 0) found = 1;
    }
    if (found) atomicOr(&s_found, 1);
    __syncthreads();
    if (threadIdx.x == 0) *flag = s_found;   // 1 => bytes, 0 => int32
}

__global__ __launch_bounds__(256, 2) void fused_sparse_attn(
        const float* __restrict__ q, const float* __restrict__ k,
        const float* __restrict__ v, const void* __restrict__ mask,
        const int* __restrict__ fmt_flag,
        float* __restrict__ out, float* __restrict__ attn) {
    const int lane = threadIdx.x & 63;
    const int wave = threadIdx.x >> 6;
    const int quad = lane >> 4;
    const int l15  = lane & 15;
    const int qt = blockIdx.x, b = blockIdx.y;
    const int rowbase = b * SEQQ + qt * 64 + wave * 16;  // wave's first row

    __shared__ unsigned short klds[2 * 128 * 64];   // 32 KB hi/lo K tile
    __shared__ float          cval[64 * CSTR];      // 24.8 KB candidate vals
    __shared__ unsigned short cidx[64 * CSTR];      // 12.4 KB candidate cols
    __shared__ int            ccnt[64];
    __shared__ float          smax[64];

    if (threadIdx.x < 64) ccnt[threadIdx.x] = 0;

    const int mask_is_byte = fmt_flag ? *fmt_flag : 1;
    const unsigned char* m8  = (const unsigned char*)mask;
    const int*           m32 = (const int*)mask;

    // Q A-fragments (row = rowbase + l15), scaled by 1/8, hi/lo split
    const float* qrow = q + (size_t)(rowbase + l15) * DHEAD;
    short8 a_hi[2], a_lo[2];
    #pragma unroll
    for (int kc = 0; kc < 2; ++kc) {
        const float4* src = (const float4*)(qrow + kc * 32 + quad * 8);
        float4 f0 = src[0], f1 = src[1];
        float fv[8] = {f0.x, f0.y, f0.z, f0.w, f1.x, f1.y, f1.z, f1.w};
        cvt_hilo8(fv, 0.125f, &a_hi[kc], &a_lo[kc]);
    }

    float rmax_reg[4] = {-FLT_MAX, -FLT_MAX, -FLT_MAX, -FLT_MAX};
    const float* kb = k + (size_t)b * SEQK * DHEAD;

    for (int kt = 0; kt < 8; ++kt) {
        __syncthreads();   // protect klds reuse across iterations
        const float* kbase = kb + (size_t)kt * 128 * DHEAD;
        #pragma unroll
        for (int it = 0; it < 4; ++it) {
            int e   = threadIdx.x + 256 * it;   // 1024 groups of 8 elems
            int key = e >> 3, db = e & 7;
            const float4* src = (const float4*)(kbase + key * DHEAD + db * 8);
            float4 f0 = src[0], f1 = src[1];
            float fv[8] = {f0.x, f0.y, f0.z, f0.w, f1.x, f1.y, f1.z, f1.w};
            short8 hi, lo;
            cvt_hilo8(fv, 1.0f, &hi, &lo);
            int off = key * 64 + ((db ^ (key & 7)) * 8);
            *(short8*)(klds + off)        = hi;
            *(short8*)(klds + 8192 + off) = lo;
        }
        __syncthreads();

        // scores for wave's 16 rows x 128 keys
        float sacc[8][4];
        #pragma unroll
        for (int g = 0; g < 8; ++g) {
            int key = g * 16 + l15;
            short8 b_hi[2], b_lo[2];
            #pragma unroll
            for (int kc = 0; kc < 2; ++kc) {
                int db  = kc * 4 + quad;
                int off = key * 64 + ((db ^ (key & 7)) * 8);
                b_hi[kc] = *(const short8*)(klds + off);
                b_lo[kc] = *(const short8*)(klds + 8192 + off);
            }
            f32x4 acc = {0.f, 0.f, 0.f, 0.f};
            #pragma unroll
            for (int kc = 0; kc < 2; ++kc) {
                acc = __builtin_amdgcn_mfma_f32_16x16x32_bf16(a_hi[kc], b_hi[kc], acc, 0, 0, 0);
                acc = __builtin_amdgcn_mfma_f32_16x16x32_bf16(a_lo[kc], b_hi[kc], acc, 0, 0, 0);
                acc = __builtin_amdgcn_mfma_f32_16x16x32_bf16(a_hi[kc], b_lo[kc], acc, 0, 0, 0);
            }
            // C layout: col = l15, row = quad*4 + r
            int colg = kt * 128 + g * 16 + l15;
            #pragma unroll
            for (int r = 0; r < 4; ++r) {
                int rowg = rowbase + quad * 4 + r;
                bool mm = mask_is_byte
                    ? (m8[(size_t)rowg * SEQK + colg] != 0)
                    : (m32[(size_t)rowg * SEQK + colg] != 0);
                sacc[g][r] = mm ? -FLT_MAX : acc[r];
            }
        }

        // update running row maxes (reduce over the 16 l15 lanes of a quad)
        #pragma unroll
        for (int r = 0; r < 4; ++r) {
            float tm = sacc[0][r];
            #pragma unroll
            for (int g = 1; g < 8; ++g) tm = fmaxf(tm, sacc[g][r]);
            #pragma unroll
            for (int off = 8; off >= 1; off >>= 1)
                tm = fmaxf(tm, __shfl_xor(tm, off, 64));
            rmax_reg[r] = fmaxf(rmax_reg[r], tm);
        }

        // collect candidates: s > rowmax - 1 (superset of final support)
        #pragma unroll
        for (int g = 0; g < 8; ++g) {
            #pragma unroll
            for (int r = 0; r < 4; ++r) {
                float sv = sacc[g][r];
                if (sv > rmax_reg[r] - 1.0f) {
                    int wrow = wave * 16 + quad * 4 + r;
                    int pos = atomicAdd(&ccnt[wrow], 1);
                    if (pos < CAP) {
                        cval[wrow * CSTR + pos] = sv;
                        cidx[wrow * CSTR + pos] =
                            (unsigned short)(kt * 128 + g * 16 + l15);
                    }
                }
            }
        }

        // zero-fill this tile's attn region (wave's 16 rows x 128 cols)
        float4 z4 = {0.f, 0.f, 0.f, 0.f};
        #pragma unroll
        for (int rep = 0; rep < 8; ++rep) {
            int linear = rep * 64 + lane;
            int rl = linear >> 5, c4 = linear & 31;
            *(float4*)(attn + (size_t)(rowbase + rl) * SEQK + kt * 128 + c4 * 4) = z4;
        }
    }

    if (l15 == 0) {
        #pragma unroll
        for (int r = 0; r < 4; ++r)
            smax[wave * 16 + quad * 4 + r] = rmax_reg[r];
    }
    __syncthreads();   // lists/smax visible; attn zero-stores drained

    const float* vb = v + (size_t)b * SEQK * DHEAD;

    for (int rl = 0; rl < 16; ++rl) {
        const int wrow = wave * 16 + rl;
        const int rowg = rowbase + rl;
        const int n    = ccnt[wrow];
        float* arow = attn + (size_t)rowg * SEQK;

        if (n <= CAP) {
            float tau;
            if (n == 0) {
                tau = FLT_MAX;    // fully-masked row -> attn stays 0, out = 0
            } else {
                float mx = smax[wrow];
                float c0 = (lane < n)      ? cval[wrow * CSTR + lane]      : -FLT_MAX;
                float c1 = (lane + 64 < n) ? cval[wrow * CSTR + lane + 64] : -FLT_MAX;
                float thr = mx - 1.0f;     // valid seed: tau* >= mx - 1
                int cnt_prev = -1;
                tau = 0.f;
                for (int it = 0; it < 32; ++it) {
                    float lsum = 0.f; int lcnt = 0;
                    if (c0 > thr) { lsum += c0; ++lcnt; }
                    if (c1 > thr) { lsum += c1; ++lcnt; }
                    #pragma unroll
                    for (int off = 32; off >= 1; off >>= 1) {
                        lsum += __shfl_xor(lsum, off, 64);
                        lcnt += __shfl_xor(lcnt, off, 64);
                    }
                    tau = (lsum - 1.0f) / (float)lcnt;
                    if (lcnt == cnt_prev) break;
                    cnt_prev = lcnt;
                    thr = tau;
                }
            }
            // PV + scatter, 8 v-rows in flight to hide L2 latency
            float oacc = 0.f;
            for (int e0 = 0; e0 < n; e0 += 8) {
                float pv[8]; int ix[8];
                #pragma unroll
                for (int u = 0; u < 8; ++u) {
                    int e = e0 + u;
                    if (e < n) {
                        pv[u] = cval[wrow * CSTR + e] - tau;
                        ix[u] = cidx[wrow * CSTR + e];
                    } else { pv[u] = 0.f; ix[u] = 0; }
                }
                float vv[8];
                #pragma unroll
                for (int u = 0; u < 8; ++u)
                    vv[u] = vb[(size_t)ix[u] * DHEAD + lane];
                #pragma unroll
                for (int u = 0; u < 8; ++u) {
                    float p = pv[u] > 0.f ? pv[u] : 0.f;
                    oacc = fmaf(p, vv[u], oacc);
                    if (pv[u] > 0.f && lane == 0) arow[ix[u]] = pv[u];
                }
            }
            out[(size_t)rowg * DHEAD + lane] = oacc;
        } else {
            // ---- overflow fallback (~never): exact fp32 full-row redo ----
            const float4* q4 = (const float4*)(q + (size_t)rowg * DHEAD);
            float s[16];
            float fmx = -FLT_MAX;
            #pragma unroll 2
            for (int t = 0; t < 16; ++t) {
                const float4* k4 =
                    (const float4*)(kb + (size_t)(lane + 64 * t) * DHEAD);
                float a0 = 0.f, a1 = 0.f, a2 = 0.f, a3 = 0.f;
                #pragma unroll
                for (int i = 0; i < 16; ++i) {
                    float4 kv = k4[i], qv = q4[i];
                    a0 = fmaf(qv.x, kv.x, a0);
                    a1 = fmaf(qv.y, kv.y, a1);
                    a2 = fmaf(qv.z, kv.z, a2);
                    a3 = fmaf(qv.w, kv.w, a3);
                }
                float acc = ((a0 + a1) + (a2 + a3)) * 0.125f;
                bool mm = mask_is_byte
                    ? (m8[(size_t)rowg * SEQK + lane + 64 * t] != 0)
                    : (m32[(size_t)rowg * SEQK + lane + 64 * t] != 0);
                s[t] = mm ? -FLT_MAX : acc;
                fmx = fmaxf(fmx, s[t]);
            }
            #pragma unroll
            for (int off = 32; off >= 1; off >>= 1)
                fmx = fmaxf(fmx, __shfl_xor(fmx, off, 64));
            float thr = fmx - 1.0f, tau = 0.f;
            int cnt_prev = -1;
            for (int it = 0; it < 32; ++it) {
                float lsum = 0.f; int lcnt = 0;
                #pragma unroll
                for (int t = 0; t < 16; ++t)
                    if (s[t] > thr) { lsum += s[t]; ++lcnt; }
                #pragma unroll
                for (int off = 32; off >= 1; off >>= 1) {
                    lsum += __shfl_xor(lsum, off, 64);
                    lcnt += __shfl_xor(lcnt, off, 64);
                }
                tau = (lsum - 1.0f) / (float)lcnt;
                if (lcnt == cnt_prev) break;
                cnt_prev = lcnt;
                thr = tau;
            }
            float p[16];
            float oacc = 0.f;
            #pragma unroll
            for (int t = 0; t < 16; ++t) {
                float pvv = s[t] - tau;
                p[t] = pvv > 0.f ? pvv : 0.f;
                arow[lane + 64 * t] = p[t];
                unsigned long long mball = __ballot(p[t] > 0.f);
                while (mball) {
                    int src = __ffsll(mball) - 1;
                    mball &= mball - 1;
                    float pj = __shfl(p[t], src);
                    oacc = fmaf(pj, vb[(size_t)(src + 64 * t) * DHEAD + lane], oacc);
                }
            }
            out[(size_t)rowg * DHEAD + lane] = oacc;
        }
    }
}

extern "C" void kernel_launch(void* const* d_in, const int* in_sizes, int n_in,
                              void* d_out, int out_size, void* d_ws, size_t ws_size,
                              hipStream_t stream) {
    const float* q = (const float*)d_in[0];
    const float* k = (const float*)d_in[1];
    const float* v = (const float*)d_in[2];
    const void*  m = d_in[3];

    float* out  = (float*)d_out;
    float* attn = out + (size_t)BATCH * SEQQ * DHEAD;

    int* flag = nullptr;
    if (ws_size >= sizeof(int)) {
        flag = (int*)d_ws;
        detect_mask_fmt<<<1, 256, 0, stream>>>((const unsigned char*)m, flag);
    }

    dim3 grid(SEQQ / 64, BATCH);
    fused_sparse_attn<<<grid, 256, 0, stream>>>(q, k, v, m, flag, out, attn);
}

// Round 5
// 695.815 us; speedup vs baseline: 1.4274x; 1.4274x over previous
//
#include <hip/hip_runtime.h>
#include <float.h>

// Sparsemax attention, fp32 in/out. B=64, Lq=Lk=1024, D=64.
// d_out = out[B,Lq,D] ++ attn[B,Lq,Lk], fp32.
//
// R5 = R2's proven two-kernel split, with the intermediate raw-score buffer
// stored as BF16 (halves the 268 MB write + 268 MB read round-trip; adds
// ~0.005 abs error vs a 0.0888 threshold). Fused single-kernel designs were
// abandoned: R3 correct-but-slow (545us), R4 had an unexplained replay race.
//
//   A) score_kernel: S = (Q/8)·K^T via bf16 MFMA hi/lo split (3 passes,
//      ~fp32 accuracy, proven R2). Stores S as bf16.
//      S lives in d_ws if big enough, else packed into the FIRST HALF of each
//      attn row's own fp32 slot (row-private: B reads its row's bf16 before
//      overwriting that same slot with fp32 attn — same-wave load-then-store,
//      no cross-block hazard).
//   B) sparsemax_pv: wave per row; coalesced bf16x4 score + mask loads; exact
//      Michelot tau; attn = relu(s-tau) written coalesced; sparse PV via
//      ballot+shfl over the support (~5-30 keys/row). Identical to R2 except
//      the S load path.

#define BATCH    64
#define SEQQ     1024
#define SEQK     1024
#define DHEAD    64

typedef short short8 __attribute__((ext_vector_type(8)));
typedef float f32x4  __attribute__((ext_vector_type(4)));

__device__ __forceinline__ unsigned short bf16_rne(float f) {
    unsigned u = __float_as_uint(f);
    u += 0x7fffu + ((u >> 16) & 1u);
    return (unsigned short)(u >> 16);
}

__device__ __forceinline__ void cvt_hilo8(const float* fv, float scale,
                                          short8* hi, short8* lo) {
    #pragma unroll
    for (int j = 0; j < 8; ++j) {
        float f = fv[j] * scale;
        unsigned short hb = bf16_rne(f);
        float hf = __uint_as_float((unsigned)hb << 16);
        (*hi)[j] = (short)hb;
        (*lo)[j] = (short)bf16_rne(f - hf);
    }
}

// ---- mask dtype detector: 1-byte bools vs int32 0/1 (proven R1-R4) --------
__global__ void detect_mask_fmt(const unsigned char* __restrict__ m,
                                int* __restrict__ flag) {
    __shared__ int s_found;
    if (threadIdx.x == 0) s_found = 0;
    __syncthreads();
    int found = 0;
    for (int o = threadIdx.x; o < 65536; o += 256) {
        if ((o & 3) != 0 && m[o] != 0) found = 1;
    }
    if (found) atomicOr(&s_found, 1);
    __syncthreads();
    if (threadIdx.x == 0) *flag = s_found;   // 1 => bytes, 0 => int32
}

// ---- kernel A: raw scores via MFMA (hi/lo bf16 split), bf16 output --------
// grid (kt=8, qt=16, b=64); block 256 = 4 waves; wave w -> 16 q-rows strip.
__global__ __launch_bounds__(256) void score_kernel(
        const float* __restrict__ q, const float* __restrict__ k,
        unsigned short* __restrict__ sbuf, int pitch) {
    const int lane = threadIdx.x & 63;
    const int wave = threadIdx.x >> 6;
    const int quad = lane >> 4;
    const int l15  = lane & 15;
    const int kt = blockIdx.x, qt = blockIdx.y, b = blockIdx.z;

    // [hl][key(128)][d(64)] ushort, 16B-group XOR-swizzled on d-block
    __shared__ unsigned short klds[2 * 128 * 64];

    const float* kbase = k + ((size_t)b * SEQK + kt * 128) * DHEAD;
    #pragma unroll
    for (int it = 0; it < 4; ++it) {
        int e   = threadIdx.x + 256 * it;    // 1024 groups of 8 elems
        int key = e >> 3, db = e & 7;
        const float4* src = (const float4*)(kbase + key * DHEAD + db * 8);
        float4 f0 = src[0], f1 = src[1];
        float fv[8] = {f0.x, f0.y, f0.z, f0.w, f1.x, f1.y, f1.z, f1.w};
        short8 hi, lo;
        cvt_hilo8(fv, 1.0f, &hi, &lo);
        int off = key * 64 + ((db ^ (key & 7)) * 8);   // ushort units
        *(short8*)(klds + off)        = hi;
        *(short8*)(klds + 8192 + off) = lo;
    }
    __syncthreads();

    // A-frags: lane holds Q[qbase + l15][kc*32 + quad*8 + j], scaled by 1/8
    const float* qrow =
        q + ((size_t)b * SEQQ + qt * 64 + wave * 16 + l15) * DHEAD;
    short8 a_hi[2], a_lo[2];
    #pragma unroll
    for (int kc = 0; kc < 2; ++kc) {
        const float4* src = (const float4*)(qrow + kc * 32 + quad * 8);
        float4 f0 = src[0], f1 = src[1];
        float fv[8] = {f0.x, f0.y, f0.z, f0.w, f1.x, f1.y, f1.z, f1.w};
        cvt_hilo8(fv, 0.125f, &a_hi[kc], &a_lo[kc]);
    }

    unsigned short* srow =
        sbuf + ((size_t)b * SEQQ + qt * 64 + wave * 16) * (size_t)pitch
             + kt * 128;
    #pragma unroll
    for (int g = 0; g < 8; ++g) {
        int key = g * 16 + l15;
        short8 b_hi[2], b_lo[2];
        #pragma unroll
        for (int kc = 0; kc < 2; ++kc) {
            int db  = kc * 4 + quad;
            int off = key * 64 + ((db ^ (key & 7)) * 8);
            b_hi[kc] = *(const short8*)(klds + off);
            b_lo[kc] = *(const short8*)(klds + 8192 + off);
        }
        f32x4 acc = {0.f, 0.f, 0.f, 0.f};
        #pragma unroll
        for (int kc = 0; kc < 2; ++kc) {
            acc = __builtin_amdgcn_mfma_f32_16x16x32_bf16(a_hi[kc], b_hi[kc], acc, 0, 0, 0);
            acc = __builtin_amdgcn_mfma_f32_16x16x32_bf16(a_lo[kc], b_hi[kc], acc, 0, 0, 0);
            acc = __builtin_amdgcn_mfma_f32_16x16x32_bf16(a_hi[kc], b_lo[kc], acc, 0, 0, 0);
        }
        // C layout: col = l15, row = quad*4 + r
        #pragma unroll
        for (int r = 0; r < 4; ++r)
            srow[(size_t)(quad * 4 + r) * (size_t)pitch + g * 16 + l15] =
                bf16_rne(acc[r]);
    }
}

// ---- kernel B: sparsemax + sparse PV, one wave per row --------------------
__global__ __launch_bounds__(256) void sparsemax_pv(
        const float* __restrict__ v, const void* __restrict__ mask,
        const int* __restrict__ fmt_flag,
        float* __restrict__ out, float* __restrict__ attn,
        const unsigned short* __restrict__ sbuf, int pitch) {
    const int lane = threadIdx.x & 63;
    const int wave = threadIdx.x >> 6;
    const int row  = blockIdx.x * 4 + wave;
    const int b    = row >> 10;
    float* arow = attn + (size_t)row * SEQK;
    const int mask_is_byte = fmt_flag ? *fmt_flag : 1;

    // lane holds keys 4*(lane+64t)+c, t=0..3, c=0..3 (coalesced ushort4 = 8B)
    const ushort4* s4 =
        (const ushort4*)(sbuf + (size_t)row * (size_t)pitch);
    float s[16];
    #pragma unroll
    for (int t = 0; t < 4; ++t) {
        ushort4 u = s4[lane + 64 * t];
        s[4*t+0] = __uint_as_float((unsigned)u.x << 16);
        s[4*t+1] = __uint_as_float((unsigned)u.y << 16);
        s[4*t+2] = __uint_as_float((unsigned)u.z << 16);
        s[4*t+3] = __uint_as_float((unsigned)u.w << 16);
    }
    if (mask_is_byte) {
        const unsigned* m32 =
            (const unsigned*)((const unsigned char*)mask + (size_t)row * SEQK);
        #pragma unroll
        for (int t = 0; t < 4; ++t) {
            unsigned m = m32[lane + 64 * t];
            if (m & 0x000000ffu) s[4*t+0] = -FLT_MAX;
            if (m & 0x0000ff00u) s[4*t+1] = -FLT_MAX;
            if (m & 0x00ff0000u) s[4*t+2] = -FLT_MAX;
            if (m & 0xff000000u) s[4*t+3] = -FLT_MAX;
        }
    } else {
        const int4* m4 = (const int4*)((const int*)mask + (size_t)row * SEQK);
        #pragma unroll
        for (int t = 0; t < 4; ++t) {
            int4 m = m4[lane + 64 * t];
            if (m.x) s[4*t+0] = -FLT_MAX;
            if (m.y) s[4*t+1] = -FLT_MAX;
            if (m.z) s[4*t+2] = -FLT_MAX;
            if (m.w) s[4*t+3] = -FLT_MAX;
        }
    }

    float mx = -FLT_MAX;
    #pragma unroll
    for (int i = 0; i < 16; ++i) mx = fmaxf(mx, s[i]);
    #pragma unroll
    for (int off = 32; off >= 1; off >>= 1)
        mx = fmaxf(mx, __shfl_xor(mx, off, 64));

    if (mx <= -FLT_MAX) {   // fully masked row -> zeros
        float4 z = {0.f, 0.f, 0.f, 0.f};
        #pragma unroll
        for (int t = 0; t < 4; ++t) ((float4*)arow)[lane + 64 * t] = z;
        out[(size_t)row * DHEAD + lane] = 0.f;
        return;
    }

    // Michelot: seed thr = mx-1 (tau* >= mx-1); A shrinks to exact support.
    float thr = mx - 1.0f, tau = 0.f;
    int cnt_prev = -1;
    for (int it = 0; it < 32; ++it) {
        float lsum = 0.f; int lcnt = 0;
        #pragma unroll
        for (int i = 0; i < 16; ++i)
            if (s[i] > thr) { lsum += s[i]; lcnt++; }
        #pragma unroll
        for (int off = 32; off >= 1; off >>= 1) {
            lsum += __shfl_xor(lsum, off, 64);
            lcnt += __shfl_xor(lcnt, off, 64);
        }
        tau = (lsum - 1.0f) / (float)lcnt;
        if (lcnt == cnt_prev) break;
        cnt_prev = lcnt;
        thr = tau;
    }

    float p[16];
    #pragma unroll
    for (int i = 0; i < 16; ++i) {
        float pv = s[i] - tau;
        p[i] = pv > 0.f ? pv : 0.f;
    }
    #pragma unroll
    for (int t = 0; t < 4; ++t) {
        float4 f = {p[4*t+0], p[4*t+1], p[4*t+2], p[4*t+3]};
        ((float4*)arow)[lane + 64 * t] = f;
    }

    // sparse PV: support is ~5-30 keys; v row loads are lane-contiguous
    const float* vbase = v + (size_t)b * SEQK * DHEAD;
    float oacc = 0.f;
    #pragma unroll
    for (int t = 0; t < 4; ++t) {
        #pragma unroll
        for (int c = 0; c < 4; ++c) {
            int i = 4 * t + c;
            unsigned long long mball = __ballot(p[i] > 0.f);
            while (mball) {
                int src = __ffsll(mball) - 1;
                mball &= mball - 1;
                float pj = __shfl(p[i], src);
                int key = 4 * (src + 64 * t) + c;
                oacc = fmaf(pj, vbase[(size_t)key * DHEAD + lane], oacc);
            }
        }
    }
    out[(size_t)row * DHEAD + lane] = oacc;
}

extern "C" void kernel_launch(void* const* d_in, const int* in_sizes, int n_in,
                              void* d_out, int out_size, void* d_ws, size_t ws_size,
                              hipStream_t stream) {
    const float* q = (const float*)d_in[0];
    const float* k = (const float*)d_in[1];
    const float* v = (const float*)d_in[2];
    const void*  m = d_in[3];

    float* out  = (float*)d_out;
    float* attn = out + (size_t)BATCH * SEQQ * DHEAD;

    int* flag = nullptr;
    if (ws_size >= sizeof(int)) {
        flag = (int*)d_ws;
        detect_mask_fmt<<<1, 256, 0, stream>>>((const unsigned char*)m, flag);
    }

    // S (bf16) placement: d_ws if it fits (after a 16-byte flag header),
    // else packed into the first half of each attn row's fp32 slot
    // (pitch 2048 bf16 = 4096 B = one row slot; row-private RMW in kernel B).
    const size_t s_elems = (size_t)BATCH * SEQQ * SEQK;
    unsigned short* sbuf;
    int pitch;
    if (ws_size >= 16 + s_elems * sizeof(unsigned short)) {
        sbuf  = (unsigned short*)d_ws + 8;   // +16 bytes, past the flag
        pitch = SEQK;                        // contiguous
    } else {
        sbuf  = (unsigned short*)attn;       // in-place, strided
        pitch = 2 * SEQK;
    }

    dim3 gridA(SEQK / 128, SEQQ / 64, BATCH);
    score_kernel<<<gridA, 256, 0, stream>>>(q, k, sbuf, pitch);

    sparsemax_pv<<<(BATCH * SEQQ) / 4, 256, 0, stream>>>(
        v, m, flag, out, attn, sbuf, pitch);
}

// Round 7
// 682.300 us; speedup vs baseline: 1.4557x; 1.0198x over previous
//
#include <hip/hip_runtime.h>
#include <float.h>

// Sparsemax attention, fp32 in/out. B=64, Lq=Lk=1024, D=64.
// d_out = out[B,Lq,D] ++ attn[B,Lq,Lk], fp32.
//
// R7 = R6 with the compile fix: __builtin_nontemporal_store needs an
// ext_vector_type pointer, not HIP's float4 class -> store via f32x4.
//   A) score_kernel: kt-loop inside the block (grid = qt x b = 1024).
//      Q fragments converted once per block, each K tile converted once.
//      Block mapping x = qt*64 + b pins a batch's 16 blocks to XCD b%8.
//      S stored bf16 (proven R5, absmax 0.0657 < 0.0888).
//   B) sparsemax_pv: LDS-buffered p (broadcast ds_read) + group-of-4
//      support extraction with 4 independent v-loads in flight; attn
//      stores nontemporal. Accumulation order unchanged vs R5.

#define BATCH    64
#define SEQQ     1024
#define SEQK     1024
#define DHEAD    64

typedef short short8 __attribute__((ext_vector_type(8)));
typedef float f32x4  __attribute__((ext_vector_type(4)));

__device__ __forceinline__ unsigned short bf16_rne(float f) {
    unsigned u = __float_as_uint(f);
    u += 0x7fffu + ((u >> 16) & 1u);
    return (unsigned short)(u >> 16);
}

__device__ __forceinline__ void cvt_hilo8(const float* fv, float scale,
                                          short8* hi, short8* lo) {
    #pragma unroll
    for (int j = 0; j < 8; ++j) {
        float f = fv[j] * scale;
        unsigned short hb = bf16_rne(f);
        float hf = __uint_as_float((unsigned)hb << 16);
        (*hi)[j] = (short)hb;
        (*lo)[j] = (short)bf16_rne(f - hf);
    }
}

// ---- mask dtype detector: 1-byte bools vs int32 0/1 (proven R1-R5) --------
__global__ void detect_mask_fmt(const unsigned char* __restrict__ m,
                                int* __restrict__ flag) {
    __shared__ int s_found;
    if (threadIdx.x == 0) s_found = 0;
    __syncthreads();
    int found = 0;
    for (int o = threadIdx.x; o < 65536; o += 256) {
        if ((o & 3) != 0 && m[o] != 0) found = 1;
    }
    if (found) atomicOr(&s_found, 1);
    __syncthreads();
    if (threadIdx.x == 0) *flag = s_found;   // 1 => bytes, 0 => int32
}

// ---- kernel A: raw scores via MFMA (hi/lo bf16 split), bf16 output --------
// grid 1024: x = qt*64 + b (so x%8 = b%8 -> per-batch XCD pinning).
// Block: 4 waves, 64 q rows; loops all 8 K tiles of 128 keys.
__global__ __launch_bounds__(256) void score_kernel(
        const float* __restrict__ q, const float* __restrict__ k,
        unsigned short* __restrict__ sbuf, int pitch) {
    const int lane = threadIdx.x & 63;
    const int wave = threadIdx.x >> 6;
    const int quad = lane >> 4;
    const int l15  = lane & 15;
    const int qt = blockIdx.x >> 6;
    const int b  = blockIdx.x & 63;

    // [hl][key(128)][d(64)] ushort, 16B-group XOR-swizzled on d-block
    __shared__ unsigned short klds[2 * 128 * 64];

    // Q A-frags once: lane holds Q[rowbase + l15][kc*32 + quad*8 + j] / 8
    const float* qrow =
        q + ((size_t)b * SEQQ + qt * 64 + wave * 16 + l15) * DHEAD;
    short8 a_hi[2], a_lo[2];
    #pragma unroll
    for (int kc = 0; kc < 2; ++kc) {
        const float4* src = (const float4*)(qrow + kc * 32 + quad * 8);
        float4 f0 = src[0], f1 = src[1];
        float fv[8] = {f0.x, f0.y, f0.z, f0.w, f1.x, f1.y, f1.z, f1.w};
        cvt_hilo8(fv, 0.125f, &a_hi[kc], &a_lo[kc]);
    }

    const float* kb = k + (size_t)b * SEQK * DHEAD;
    unsigned short* srow0 =
        sbuf + ((size_t)b * SEQQ + qt * 64 + wave * 16) * (size_t)pitch;

    for (int kt = 0; kt < 8; ++kt) {
        __syncthreads();   // guard klds reuse across kt iterations
        const float* kbase = kb + (size_t)kt * 128 * DHEAD;
        #pragma unroll
        for (int it = 0; it < 4; ++it) {
            int e   = threadIdx.x + 256 * it;    // 1024 groups of 8 elems
            int key = e >> 3, db = e & 7;
            const float4* src = (const float4*)(kbase + key * DHEAD + db * 8);
            float4 f0 = src[0], f1 = src[1];
            float fv[8] = {f0.x, f0.y, f0.z, f0.w, f1.x, f1.y, f1.z, f1.w};
            short8 hi, lo;
            cvt_hilo8(fv, 1.0f, &hi, &lo);
            int off = key * 64 + ((db ^ (key & 7)) * 8);   // ushort units
            *(short8*)(klds + off)        = hi;
            *(short8*)(klds + 8192 + off) = lo;
        }
        __syncthreads();

        unsigned short* srow = srow0 + kt * 128;
        #pragma unroll
        for (int g = 0; g < 8; ++g) {
            int key = g * 16 + l15;
            short8 b_hi[2], b_lo[2];
            #pragma unroll
            for (int kc = 0; kc < 2; ++kc) {
                int db  = kc * 4 + quad;
                int off = key * 64 + ((db ^ (key & 7)) * 8);
                b_hi[kc] = *(const short8*)(klds + off);
                b_lo[kc] = *(const short8*)(klds + 8192 + off);
            }
            f32x4 acc = {0.f, 0.f, 0.f, 0.f};
            #pragma unroll
            for (int kc = 0; kc < 2; ++kc) {
                acc = __builtin_amdgcn_mfma_f32_16x16x32_bf16(a_hi[kc], b_hi[kc], acc, 0, 0, 0);
                acc = __builtin_amdgcn_mfma_f32_16x16x32_bf16(a_lo[kc], b_hi[kc], acc, 0, 0, 0);
                acc = __builtin_amdgcn_mfma_f32_16x16x32_bf16(a_hi[kc], b_lo[kc], acc, 0, 0, 0);
            }
            // C layout: col = l15, row = quad*4 + r
            #pragma unroll
            for (int r = 0; r < 4; ++r)
                srow[(size_t)(quad * 4 + r) * (size_t)pitch + g * 16 + l15] =
                    bf16_rne(acc[r]);
        }
    }
}

// ---- kernel B: sparsemax + sparse PV, one wave per row --------------------
__global__ __launch_bounds__(256) void sparsemax_pv(
        const float* __restrict__ v, const void* __restrict__ mask,
        const int* __restrict__ fmt_flag,
        float* __restrict__ out, float* __restrict__ attn,
        const unsigned short* __restrict__ sbuf, int pitch) {
    const int lane = threadIdx.x & 63;
    const int wave = threadIdx.x >> 6;
    const int row  = blockIdx.x * 4 + wave;
    const int b    = row >> 10;
    float* arow = attn + (size_t)row * SEQK;
    const int mask_is_byte = fmt_flag ? *fmt_flag : 1;

    __shared__ float pbuf[4][SEQK];   // per-wave p values, 16 KB total

    // lane holds keys 4*lane + 256*t + c, t=0..3, c=0..3 (coalesced 8B)
    const ushort4* s4 =
        (const ushort4*)(sbuf + (size_t)row * (size_t)pitch);
    float s[16];
    #pragma unroll
    for (int t = 0; t < 4; ++t) {
        ushort4 u = s4[lane + 64 * t];
        s[4*t+0] = __uint_as_float((unsigned)u.x << 16);
        s[4*t+1] = __uint_as_float((unsigned)u.y << 16);
        s[4*t+2] = __uint_as_float((unsigned)u.z << 16);
        s[4*t+3] = __uint_as_float((unsigned)u.w << 16);
    }
    if (mask_is_byte) {
        const unsigned* m32 =
            (const unsigned*)((const unsigned char*)mask + (size_t)row * SEQK);
        #pragma unroll
        for (int t = 0; t < 4; ++t) {
            unsigned m = m32[lane + 64 * t];
            if (m & 0x000000ffu) s[4*t+0] = -FLT_MAX;
            if (m & 0x0000ff00u) s[4*t+1] = -FLT_MAX;
            if (m & 0x00ff0000u) s[4*t+2] = -FLT_MAX;
            if (m & 0xff000000u) s[4*t+3] = -FLT_MAX;
        }
    } else {
        const int4* m4 = (const int4*)((const int*)mask + (size_t)row * SEQK);
        #pragma unroll
        for (int t = 0; t < 4; ++t) {
            int4 m = m4[lane + 64 * t];
            if (m.x) s[4*t+0] = -FLT_MAX;
            if (m.y) s[4*t+1] = -FLT_MAX;
            if (m.z) s[4*t+2] = -FLT_MAX;
            if (m.w) s[4*t+3] = -FLT_MAX;
        }
    }

    float mx = -FLT_MAX;
    #pragma unroll
    for (int i = 0; i < 16; ++i) mx = fmaxf(mx, s[i]);
    #pragma unroll
    for (int off = 32; off >= 1; off >>= 1)
        mx = fmaxf(mx, __shfl_xor(mx, off, 64));

    if (mx <= -FLT_MAX) {   // fully masked row -> zeros
        f32x4 z = {0.f, 0.f, 0.f, 0.f};
        #pragma unroll
        for (int t = 0; t < 4; ++t)
            __builtin_nontemporal_store(z, (f32x4*)arow + lane + 64 * t);
        out[(size_t)row * DHEAD + lane] = 0.f;
        return;
    }

    // Michelot: seed thr = mx-1 (tau* >= mx-1); A shrinks to exact support.
    float thr = mx - 1.0f, tau = 0.f;
    int cnt_prev = -1;
    for (int it = 0; it < 32; ++it) {
        float lsum = 0.f; int lcnt = 0;
        #pragma unroll
        for (int i = 0; i < 16; ++i)
            if (s[i] > thr) { lsum += s[i]; lcnt++; }
        #pragma unroll
        for (int off = 32; off >= 1; off >>= 1) {
            lsum += __shfl_xor(lsum, off, 64);
            lcnt += __shfl_xor(lcnt, off, 64);
        }
        tau = (lsum - 1.0f) / (float)lcnt;
        if (lcnt == cnt_prev) break;
        cnt_prev = lcnt;
        thr = tau;
    }

    // p; attn NT-store (don't pollute L2); pbuf for broadcast reads in PV
    float p[16];
    #pragma unroll
    for (int i = 0; i < 16; ++i) {
        float pv = s[i] - tau;
        p[i] = pv > 0.f ? pv : 0.f;
    }
    #pragma unroll
    for (int t = 0; t < 4; ++t) {
        f32x4 f = {p[4*t+0], p[4*t+1], p[4*t+2], p[4*t+3]};
        __builtin_nontemporal_store(f, (f32x4*)arow + lane + 64 * t);
        *(f32x4*)&pbuf[wave][4 * (lane + 64 * t)] = f;
    }

    // sparse PV: group-of-4 extraction, independent v-loads in flight.
    // All extraction branches are wave-uniform (mb is uniform): scalar
    // branches, no divergence. Accumulation order = ascending key (as R5).
    const float* vbase = v + (size_t)b * SEQK * DHEAD;
    float oacc = 0.f;
    #pragma unroll
    for (int t = 0; t < 4; ++t) {
        #pragma unroll
        for (int c = 0; c < 4; ++c) {
            int i = 4 * t + c;
            unsigned long long mb = __ballot(p[i] > 0.f);
            while (mb) {
                int k0, k1 = -1, k2 = -1, k3 = -1;
                k0 = __ffsll(mb) - 1; mb &= mb - 1;
                if (mb) { k1 = __ffsll(mb) - 1; mb &= mb - 1; }
                if (mb) { k2 = __ffsll(mb) - 1; mb &= mb - 1; }
                if (mb) { k3 = __ffsll(mb) - 1; mb &= mb - 1; }
                int key0 = 4 * k0 + 256 * t + c;
                float pj0 = pbuf[wave][key0];
                float v0  = vbase[(size_t)key0 * DHEAD + lane];
                float pj1 = 0.f, pj2 = 0.f, pj3 = 0.f;
                float v1 = 0.f, v2 = 0.f, v3 = 0.f;
                if (k1 >= 0) {
                    int key1 = 4 * k1 + 256 * t + c;
                    pj1 = pbuf[wave][key1];
                    v1  = vbase[(size_t)key1 * DHEAD + lane];
                }
                if (k2 >= 0) {
                    int key2 = 4 * k2 + 256 * t + c;
                    pj2 = pbuf[wave][key2];
                    v2  = vbase[(size_t)key2 * DHEAD + lane];
                }
                if (k3 >= 0) {
                    int key3 = 4 * k3 + 256 * t + c;
                    pj3 = pbuf[wave][key3];
                    v3  = vbase[(size_t)key3 * DHEAD + lane];
                }
                oacc = fmaf(pj0, v0, oacc);
                if (k1 >= 0) oacc = fmaf(pj1, v1, oacc);
                if (k2 >= 0) oacc = fmaf(pj2, v2, oacc);
                if (k3 >= 0) oacc = fmaf(pj3, v3, oacc);
            }
        }
    }
    out[(size_t)row * DHEAD + lane] = oacc;
}

extern "C" void kernel_launch(void* const* d_in, const int* in_sizes, int n_in,
                              void* d_out, int out_size, void* d_ws, size_t ws_size,
                              hipStream_t stream) {
    const float* q = (const float*)d_in[0];
    const float* k = (const float*)d_in[1];
    const float* v = (const float*)d_in[2];
    const void*  m = d_in[3];

    float* out  = (float*)d_out;
    float* attn = out + (size_t)BATCH * SEQQ * DHEAD;

    int* flag = nullptr;
    if (ws_size >= sizeof(int)) {
        flag = (int*)d_ws;
        detect_mask_fmt<<<1, 256, 0, stream>>>((const unsigned char*)m, flag);
    }

    // S (bf16) placement: d_ws if it fits (after a 16-byte flag header),
    // else packed into the first half of each attn row's fp32 slot
    // (row-private read-then-overwrite in kernel B; proven R5).
    const size_t s_elems = (size_t)BATCH * SEQQ * SEQK;
    unsigned short* sbuf;
    int pitch;
    if (ws_size >= 16 + s_elems * sizeof(unsigned short)) {
        sbuf  = (unsigned short*)d_ws + 8;   // +16 bytes, past the flag
        pitch = SEQK;                        // contiguous
    } else {
        sbuf  = (unsigned short*)attn;       // in-place, strided
        pitch = 2 * SEQK;
    }

    // grid 1024: x = qt*64 + b -> x%8 = b%8 (per-batch XCD pinning)
    score_kernel<<<(SEQQ / 64) * BATCH, 256, 0, stream>>>(q, k, sbuf, pitch);

    sparsemax_pv<<<(BATCH * SEQQ) / 4, 256, 0, stream>>>(
        v, m, flag, out, attn, sbuf, pitch);
}

// Round 8
// 646.196 us; speedup vs baseline: 1.5370x; 1.0559x over previous
//
#include <hip/hip_runtime.h>
#include <float.h>

// Sparsemax attention, fp32 in/out. B=64, Lq=Lk=1024, D=64.
// d_out = out[B,Lq,D] ++ attn[B,Lq,Lk], fp32.
//
// R8 = R7 with kernel A's K-conversion hoisted out of the hot loop:
//   0) kprep: K -> hi/lo bf16 ONCE (R7 converted each tile 16x across
//      blocks; cvt was ~3072 VALU-cyc/block vs 1863 MFMA-cyc). Output is
//      stored PRE-SWIZZLED in klds layout, so...
//   A) score_kernel_dma: staging is pure DMA via global_load_lds width=16
//      (wave-uniform LDS base + lane*16; tile is lane-linear by
//      construction). Zero staging VALU. Grid/XCD mapping as R7.
//   B) sparsemax_pv: R7's proven kernel + nontemporal S/mask loads
//      (keep L2 for v). Accumulation order unchanged -> absmax identical.
// Fallbacks when ws_size is small: R7's cvt-in-loop score kernel and the
// S-in-attn placement (both proven in R5/R7).

#define BATCH    64
#define SEQQ     1024
#define SEQK     1024
#define DHEAD    64

typedef short short8 __attribute__((ext_vector_type(8)));
typedef float f32x4  __attribute__((ext_vector_type(4)));
typedef unsigned short us4v __attribute__((ext_vector_type(4)));

typedef const __attribute__((address_space(1))) unsigned int as1_cuint;
typedef __attribute__((address_space(3))) unsigned int as3_uint;
typedef __attribute__((address_space(3))) unsigned char as3_uchar;

__device__ __forceinline__ unsigned short bf16_rne(float f) {
    unsigned u = __float_as_uint(f);
    u += 0x7fffu + ((u >> 16) & 1u);
    return (unsigned short)(u >> 16);
}

__device__ __forceinline__ void cvt_hilo8(const float* fv, float scale,
                                          short8* hi, short8* lo) {
    #pragma unroll
    for (int j = 0; j < 8; ++j) {
        float f = fv[j] * scale;
        unsigned short hb = bf16_rne(f);
        float hf = __uint_as_float((unsigned)hb << 16);
        (*hi)[j] = (short)hb;
        (*lo)[j] = (short)bf16_rne(f - hf);
    }
}

// ---- mask dtype detector: 1-byte bools vs int32 0/1 (proven R1-R7) --------
__global__ void detect_mask_fmt(const unsigned char* __restrict__ m,
                                int* __restrict__ flag) {
    __shared__ int s_found;
    if (threadIdx.x == 0) s_found = 0;
    __syncthreads();
    int found = 0;
    for (int o = threadIdx.x; o < 65536; o += 256) {
        if ((o & 3) != 0 && m[o] != 0) found = 1;
    }
    if (found) atomicOr(&s_found, 1);
    __syncthreads();
    if (threadIdx.x == 0) *flag = s_found;   // 1 => bytes, 0 => int32
}

// ---- kernel 0: K -> hi/lo bf16, pre-swizzled in klds tile layout ----------
// kbuf tile (b,kt): 16384 ushorts = [hi: key(128) x d(64) swizzled][lo: same].
// Thread handles one (key, db) 8-elem group. 2048 blocks x 256.
__global__ __launch_bounds__(256) void kprep(
        const float* __restrict__ k, unsigned short* __restrict__ kbuf) {
    int gid  = blockIdx.x * 256 + threadIdx.x;    // [0, 64*1024*8)
    int db   = gid & 7;
    int keyg = (gid >> 3) & 1023;
    int b    = gid >> 13;
    int kt   = keyg >> 7;
    int key  = keyg & 127;

    const float4* src =
        (const float4*)(k + ((size_t)b * SEQK + keyg) * DHEAD + db * 8);
    float4 f0 = src[0], f1 = src[1];
    float fv[8] = {f0.x, f0.y, f0.z, f0.w, f1.x, f1.y, f1.z, f1.w};
    short8 hi, lo;
    cvt_hilo8(fv, 1.0f, &hi, &lo);

    unsigned short* tile = kbuf + (size_t)(b * 8 + kt) * 16384;
    int off = key * 64 + ((db ^ (key & 7)) * 8);   // ushort units
    *(short8*)(tile + off)        = hi;
    *(short8*)(tile + 8192 + off) = lo;
}

// ---- kernel A (fast path): scores via MFMA, DMA-staged K tiles ------------
// grid 1024: x = qt*64 + b (x%8 = b%8 -> per-batch XCD pinning).
__global__ __launch_bounds__(256) void score_kernel_dma(
        const float* __restrict__ q, const unsigned short* __restrict__ kbuf,
        unsigned short* __restrict__ sbuf, int pitch) {
    const int lane = threadIdx.x & 63;
    const int wave = threadIdx.x >> 6;
    const int quad = lane >> 4;
    const int l15  = lane & 15;
    const int qt = blockIdx.x >> 6;
    const int b  = blockIdx.x & 63;

    __shared__ unsigned short klds[2 * 128 * 64];   // 32 KB

    // Q A-frags once, scaled by 1/8, hi/lo split
    const float* qrow =
        q + ((size_t)b * SEQQ + qt * 64 + wave * 16 + l15) * DHEAD;
    short8 a_hi[2], a_lo[2];
    #pragma unroll
    for (int kc = 0; kc < 2; ++kc) {
        const float4* src = (const float4*)(qrow + kc * 32 + quad * 8);
        float4 f0 = src[0], f1 = src[1];
        float fv[8] = {f0.x, f0.y, f0.z, f0.w, f1.x, f1.y, f1.z, f1.w};
        cvt_hilo8(fv, 0.125f, &a_hi[kc], &a_lo[kc]);
    }

    unsigned short* srow0 =
        sbuf + ((size_t)b * SEQQ + qt * 64 + wave * 16) * (size_t)pitch;

    for (int kt = 0; kt < 8; ++kt) {
        __syncthreads();   // guard klds reuse across kt iterations
        // DMA 32 KB tile: 4 waves x 8 calls x (64 lanes x 16 B)
        const unsigned char* gtile =
            (const unsigned char*)(kbuf + (size_t)(b * 8 + kt) * 16384);
        {
            unsigned base = wave * 8192 + lane * 16;
            #pragma unroll
            for (int j = 0; j < 8; ++j) {
                unsigned off = base + j * 1024;
                as1_cuint* gp = (as1_cuint*)(gtile + off);
                as3_uint*  lp = (as3_uint*)((as3_uchar*)klds +
                                            (wave * 8192 + j * 1024));
                __builtin_amdgcn_global_load_lds(gp, lp, 16, 0, 0);
            }
        }
        __syncthreads();

        unsigned short* srow = srow0 + kt * 128;
        #pragma unroll
        for (int g = 0; g < 8; ++g) {
            int key = g * 16 + l15;
            short8 b_hi[2], b_lo[2];
            #pragma unroll
            for (int kc = 0; kc < 2; ++kc) {
                int db  = kc * 4 + quad;
                int off = key * 64 + ((db ^ (key & 7)) * 8);
                b_hi[kc] = *(const short8*)(klds + off);
                b_lo[kc] = *(const short8*)(klds + 8192 + off);
            }
            f32x4 acc = {0.f, 0.f, 0.f, 0.f};
            #pragma unroll
            for (int kc = 0; kc < 2; ++kc) {
                acc = __builtin_amdgcn_mfma_f32_16x16x32_bf16(a_hi[kc], b_hi[kc], acc, 0, 0, 0);
                acc = __builtin_amdgcn_mfma_f32_16x16x32_bf16(a_lo[kc], b_hi[kc], acc, 0, 0, 0);
                acc = __builtin_amdgcn_mfma_f32_16x16x32_bf16(a_hi[kc], b_lo[kc], acc, 0, 0, 0);
            }
            // C layout: col = l15, row = quad*4 + r
            #pragma unroll
            for (int r = 0; r < 4; ++r)
                srow[(size_t)(quad * 4 + r) * (size_t)pitch + g * 16 + l15] =
                    bf16_rne(acc[r]);
        }
    }
}

// ---- kernel A (fallback): R7's cvt-in-loop version ------------------------
__global__ __launch_bounds__(256) void score_kernel_cvt(
        const float* __restrict__ q, const float* __restrict__ k,
        unsigned short* __restrict__ sbuf, int pitch) {
    const int lane = threadIdx.x & 63;
    const int wave = threadIdx.x >> 6;
    const int quad = lane >> 4;
    const int l15  = lane & 15;
    const int qt = blockIdx.x >> 6;
    const int b  = blockIdx.x & 63;

    __shared__ unsigned short klds[2 * 128 * 64];

    const float* qrow =
        q + ((size_t)b * SEQQ + qt * 64 + wave * 16 + l15) * DHEAD;
    short8 a_hi[2], a_lo[2];
    #pragma unroll
    for (int kc = 0; kc < 2; ++kc) {
        const float4* src = (const float4*)(qrow + kc * 32 + quad * 8);
        float4 f0 = src[0], f1 = src[1];
        float fv[8] = {f0.x, f0.y, f0.z, f0.w, f1.x, f1.y, f1.z, f1.w};
        cvt_hilo8(fv, 0.125f, &a_hi[kc], &a_lo[kc]);
    }

    const float* kb = k + (size_t)b * SEQK * DHEAD;
    unsigned short* srow0 =
        sbuf + ((size_t)b * SEQQ + qt * 64 + wave * 16) * (size_t)pitch;

    for (int kt = 0; kt < 8; ++kt) {
        __syncthreads();
        const float* kbase = kb + (size_t)kt * 128 * DHEAD;
        #pragma unroll
        for (int it = 0; it < 4; ++it) {
            int e   = threadIdx.x + 256 * it;
            int key = e >> 3, db = e & 7;
            const float4* src = (const float4*)(kbase + key * DHEAD + db * 8);
            float4 f0 = src[0], f1 = src[1];
            float fv[8] = {f0.x, f0.y, f0.z, f0.w, f1.x, f1.y, f1.z, f1.w};
            short8 hi, lo;
            cvt_hilo8(fv, 1.0f, &hi, &lo);
            int off = key * 64 + ((db ^ (key & 7)) * 8);
            *(short8*)(klds + off)        = hi;
            *(short8*)(klds + 8192 + off) = lo;
        }
        __syncthreads();

        unsigned short* srow = srow0 + kt * 128;
        #pragma unroll
        for (int g = 0; g < 8; ++g) {
            int key = g * 16 + l15;
            short8 b_hi[2], b_lo[2];
            #pragma unroll
            for (int kc = 0; kc < 2; ++kc) {
                int db  = kc * 4 + quad;
                int off = key * 64 + ((db ^ (key & 7)) * 8);
                b_hi[kc] = *(const short8*)(klds + off);
                b_lo[kc] = *(const short8*)(klds + 8192 + off);
            }
            f32x4 acc = {0.f, 0.f, 0.f, 0.f};
            #pragma unroll
            for (int kc = 0; kc < 2; ++kc) {
                acc = __builtin_amdgcn_mfma_f32_16x16x32_bf16(a_hi[kc], b_hi[kc], acc, 0, 0, 0);
                acc = __builtin_amdgcn_mfma_f32_16x16x32_bf16(a_lo[kc], b_hi[kc], acc, 0, 0, 0);
                acc = __builtin_amdgcn_mfma_f32_16x16x32_bf16(a_hi[kc], b_lo[kc], acc, 0, 0, 0);
            }
            #pragma unroll
            for (int r = 0; r < 4; ++r)
                srow[(size_t)(quad * 4 + r) * (size_t)pitch + g * 16 + l15] =
                    bf16_rne(acc[r]);
        }
    }
}

// ---- kernel B: sparsemax + sparse PV, one wave per row --------------------
__global__ __launch_bounds__(256) void sparsemax_pv(
        const float* __restrict__ v, const void* __restrict__ mask,
        const int* __restrict__ fmt_flag,
        float* __restrict__ out, float* __restrict__ attn,
        const unsigned short* __restrict__ sbuf, int pitch) {
    const int lane = threadIdx.x & 63;
    const int wave = threadIdx.x >> 6;
    const int row  = blockIdx.x * 4 + wave;
    const int b    = row >> 10;
    float* arow = attn + (size_t)row * SEQK;
    const int mask_is_byte = fmt_flag ? *fmt_flag : 1;

    __shared__ float pbuf[4][SEQK];   // per-wave p values, 16 KB total

    // lane holds keys 4*lane + 256*t + c (coalesced 8B, nontemporal)
    const us4v* s4 = (const us4v*)(sbuf + (size_t)row * (size_t)pitch);
    float s[16];
    #pragma unroll
    for (int t = 0; t < 4; ++t) {
        us4v u = __builtin_nontemporal_load(s4 + lane + 64 * t);
        s[4*t+0] = __uint_as_float((unsigned)u[0] << 16);
        s[4*t+1] = __uint_as_float((unsigned)u[1] << 16);
        s[4*t+2] = __uint_as_float((unsigned)u[2] << 16);
        s[4*t+3] = __uint_as_float((unsigned)u[3] << 16);
    }
    if (mask_is_byte) {
        const unsigned* m32 =
            (const unsigned*)((const unsigned char*)mask + (size_t)row * SEQK);
        #pragma unroll
        for (int t = 0; t < 4; ++t) {
            unsigned m = __builtin_nontemporal_load(m32 + lane + 64 * t);
            if (m & 0x000000ffu) s[4*t+0] = -FLT_MAX;
            if (m & 0x0000ff00u) s[4*t+1] = -FLT_MAX;
            if (m & 0x00ff0000u) s[4*t+2] = -FLT_MAX;
            if (m & 0xff000000u) s[4*t+3] = -FLT_MAX;
        }
    } else {
        const int* mi = (const int*)mask + (size_t)row * SEQK;
        #pragma unroll
        for (int t = 0; t < 4; ++t) {
            int m0 = __builtin_nontemporal_load(mi + 4 * (lane + 64 * t) + 0);
            int m1 = __builtin_nontemporal_load(mi + 4 * (lane + 64 * t) + 1);
            int m2 = __builtin_nontemporal_load(mi + 4 * (lane + 64 * t) + 2);
            int m3 = __builtin_nontemporal_load(mi + 4 * (lane + 64 * t) + 3);
            if (m0) s[4*t+0] = -FLT_MAX;
            if (m1) s[4*t+1] = -FLT_MAX;
            if (m2) s[4*t+2] = -FLT_MAX;
            if (m3) s[4*t+3] = -FLT_MAX;
        }
    }

    float mx = -FLT_MAX;
    #pragma unroll
    for (int i = 0; i < 16; ++i) mx = fmaxf(mx, s[i]);
    #pragma unroll
    for (int off = 32; off >= 1; off >>= 1)
        mx = fmaxf(mx, __shfl_xor(mx, off, 64));

    if (mx <= -FLT_MAX) {   // fully masked row -> zeros
        f32x4 z = {0.f, 0.f, 0.f, 0.f};
        #pragma unroll
        for (int t = 0; t < 4; ++t)
            __builtin_nontemporal_store(z, (f32x4*)arow + lane + 64 * t);
        out[(size_t)row * DHEAD + lane] = 0.f;
        return;
    }

    // Michelot: seed thr = mx-1 (tau* >= mx-1); A shrinks to exact support.
    float thr = mx - 1.0f, tau = 0.f;
    int cnt_prev = -1;
    for (int it = 0; it < 32; ++it) {
        float lsum = 0.f; int lcnt = 0;
        #pragma unroll
        for (int i = 0; i < 16; ++i)
            if (s[i] > thr) { lsum += s[i]; lcnt++; }
        #pragma unroll
        for (int off = 32; off >= 1; off >>= 1) {
            lsum += __shfl_xor(lsum, off, 64);
            lcnt += __shfl_xor(lcnt, off, 64);
        }
        tau = (lsum - 1.0f) / (float)lcnt;
        if (lcnt == cnt_prev) break;
        cnt_prev = lcnt;
        thr = tau;
    }

    // p; attn NT-store; pbuf for broadcast reads in PV
    float p[16];
    #pragma unroll
    for (int i = 0; i < 16; ++i) {
        float pv = s[i] - tau;
        p[i] = pv > 0.f ? pv : 0.f;
    }
    #pragma unroll
    for (int t = 0; t < 4; ++t) {
        f32x4 f = {p[4*t+0], p[4*t+1], p[4*t+2], p[4*t+3]};
        __builtin_nontemporal_store(f, (f32x4*)arow + lane + 64 * t);
        *(f32x4*)&pbuf[wave][4 * (lane + 64 * t)] = f;
    }

    // sparse PV: group-of-4 extraction, independent v-loads in flight.
    const float* vbase = v + (size_t)b * SEQK * DHEAD;
    float oacc = 0.f;
    #pragma unroll
    for (int t = 0; t < 4; ++t) {
        #pragma unroll
        for (int c = 0; c < 4; ++c) {
            int i = 4 * t + c;
            unsigned long long mb = __ballot(p[i] > 0.f);
            while (mb) {
                int k0, k1 = -1, k2 = -1, k3 = -1;
                k0 = __ffsll(mb) - 1; mb &= mb - 1;
                if (mb) { k1 = __ffsll(mb) - 1; mb &= mb - 1; }
                if (mb) { k2 = __ffsll(mb) - 1; mb &= mb - 1; }
                if (mb) { k3 = __ffsll(mb) - 1; mb &= mb - 1; }
                int key0 = 4 * k0 + 256 * t + c;
                float pj0 = pbuf[wave][key0];
                float v0  = vbase[(size_t)key0 * DHEAD + lane];
                float pj1 = 0.f, pj2 = 0.f, pj3 = 0.f;
                float v1 = 0.f, v2 = 0.f, v3 = 0.f;
                if (k1 >= 0) {
                    int key1 = 4 * k1 + 256 * t + c;
                    pj1 = pbuf[wave][key1];
                    v1  = vbase[(size_t)key1 * DHEAD + lane];
                }
                if (k2 >= 0) {
                    int key2 = 4 * k2 + 256 * t + c;
                    pj2 = pbuf[wave][key2];
                    v2  = vbase[(size_t)key2 * DHEAD + lane];
                }
                if (k3 >= 0) {
                    int key3 = 4 * k3 + 256 * t + c;
                    pj3 = pbuf[wave][key3];
                    v3  = vbase[(size_t)key3 * DHEAD + lane];
                }
                oacc = fmaf(pj0, v0, oacc);
                if (k1 >= 0) oacc = fmaf(pj1, v1, oacc);
                if (k2 >= 0) oacc = fmaf(pj2, v2, oacc);
                if (k3 >= 0) oacc = fmaf(pj3, v3, oacc);
            }
        }
    }
    out[(size_t)row * DHEAD + lane] = oacc;
}

extern "C" void kernel_launch(void* const* d_in, const int* in_sizes, int n_in,
                              void* d_out, int out_size, void* d_ws, size_t ws_size,
                              hipStream_t stream) {
    const float* q = (const float*)d_in[0];
    const float* k = (const float*)d_in[1];
    const float* v = (const float*)d_in[2];
    const void*  m = d_in[3];

    float* out  = (float*)d_out;
    float* attn = out + (size_t)BATCH * SEQQ * DHEAD;

    int* flag = nullptr;
    if (ws_size >= sizeof(int)) {
        flag = (int*)d_ws;
        detect_mask_fmt<<<1, 256, 0, stream>>>((const unsigned char*)m, flag);
    }

    // ws layout: [0,16) flag | [16, 16+S) S bf16 | [16+S, 16+S+K) K hi/lo
    const size_t S_BYTES = (size_t)BATCH * SEQQ * SEQK * 2;          // 134 MB
    const size_t K_BYTES = (size_t)BATCH * SEQK * DHEAD * 2 * 2;     // 16 MB

    unsigned short* sbuf;
    int pitch;
    bool s_in_ws = ws_size >= 16 + S_BYTES;
    if (s_in_ws) {
        sbuf  = (unsigned short*)d_ws + 8;
        pitch = SEQK;
    } else {
        sbuf  = (unsigned short*)attn;   // in-place, strided (proven R5)
        pitch = 2 * SEQK;
    }

    bool k_in_ws = s_in_ws && ws_size >= 16 + S_BYTES + K_BYTES;
    if (k_in_ws) {
        unsigned short* kbuf =
            (unsigned short*)((char*)d_ws + 16 + S_BYTES);
        kprep<<<(BATCH * SEQK * 8) / 256, 256, 0, stream>>>(k, kbuf);
        score_kernel_dma<<<(SEQQ / 64) * BATCH, 256, 0, stream>>>(
            q, kbuf, sbuf, pitch);
    } else {
        score_kernel_cvt<<<(SEQQ / 64) * BATCH, 256, 0, stream>>>(
            q, k, sbuf, pitch);
    }

    sparsemax_pv<<<(BATCH * SEQQ) / 4, 256, 0, stream>>>(
        v, m, flag, out, attn, sbuf, pitch);
}